// Round 6
// baseline (1024.302 us; speedup 1.0000x reference)
//
#include <hip/hip_runtime.h>
#include <cstdint>
#include <cstddef>

#define NN 200000
#define NE 600000
#define NG 8192
#define C0 32
#define C1 128
#define C2 256
#define MLPH 256
#define NCLS 10
#define NB (3 * NN)
#define SCAN_BPB 1024
#define SCAN_NBLK ((NB + SCAN_BPB - 1) / SCAN_BPB)

typedef __attribute__((ext_vector_type(8))) short short8b;  // 8 bf16 = 4 VGPR
typedef __attribute__((ext_vector_type(4))) float f32x4;

__device__ __forceinline__ void atomAddF(float* p, float v) { unsafeAtomicAdd(p, v); }

__device__ __forceinline__ float b2f(unsigned short u) {
  union { unsigned u; float f; } v; v.u = ((unsigned)u) << 16; return v.f;
}
__device__ __forceinline__ unsigned short f2b(float f) {  // RNE
  union { float f; unsigned u; } v; v.f = f;
  return (unsigned short)((v.u + 0x7FFF + ((v.u >> 16) & 1)) >> 16);
}

// ---------------- small utility kernels ----------------
__global__ __launch_bounds__(256) void k_fill(float* __restrict__ p, int n, float v) {
  int i = blockIdx.x * 256 + threadIdx.x;
  if (i < n) p[i] = v;
}

__global__ __launch_bounds__(256) void k_counts(const int* __restrict__ batch, float* __restrict__ counts) {
  int n = blockIdx.x * 256 + threadIdx.x;
  if (n < NN) atomAddF(&counts[batch[n]], 1.f);
}

// ---------------- CSR build: histogram (= degree), scan, place ----------------
__global__ __launch_bounds__(256) void k_hist(const int* __restrict__ dst, const int* __restrict__ et,
                                              int* __restrict__ cnt) {
  int e = blockIdx.x * 256 + threadIdx.x;
  if (e < NE) atomicAdd(&cnt[et[e] * NN + dst[e]], 1);
}

__global__ __launch_bounds__(256) void k_dinvI(const int* __restrict__ cnt, float* __restrict__ dinv) {
  int i = blockIdx.x * 256 + threadIdx.x;
  if (i < NB) { int c = cnt[i]; dinv[i] = (c > 0) ? 1.f / sqrtf((float)c) : 0.f; }
}

__global__ __launch_bounds__(256) void k_scan1(const int* __restrict__ cnt, int* __restrict__ starts,
                                               int* __restrict__ bsum) {
  __shared__ int sh[256];
  const int b0 = blockIdx.x * SCAN_BPB + threadIdx.x * 4;
  int v[4]; int tot = 0;
#pragma unroll
  for (int j = 0; j < 4; j++) {
    int b = b0 + j;
    v[j] = tot;
    tot += (b < NB) ? cnt[b] : 0;
  }
  sh[threadIdx.x] = tot;
  __syncthreads();
  for (int ofs = 1; ofs < 256; ofs <<= 1) {
    int add = (threadIdx.x >= ofs) ? sh[threadIdx.x - ofs] : 0;
    __syncthreads();
    sh[threadIdx.x] += add;
    __syncthreads();
  }
  const int excl = (threadIdx.x == 0) ? 0 : sh[threadIdx.x - 1];
#pragma unroll
  for (int j = 0; j < 4; j++) {
    int b = b0 + j;
    if (b < NB) starts[b] = excl + v[j];
  }
  if (threadIdx.x == 255) bsum[blockIdx.x] = sh[255];
}

__global__ void k_scan2(int* __restrict__ bsum) {
  if (threadIdx.x == 0) {
    int acc = 0;
    for (int i = 0; i < SCAN_NBLK; i++) { int t = bsum[i]; bsum[i] = acc; acc += t; }
  }
}

__global__ __launch_bounds__(256) void k_scan3(int* __restrict__ starts, const int* __restrict__ bsum) {
  int b = blockIdx.x * 256 + threadIdx.x;
  if (b < NB) starts[b] += bsum[b / SCAN_BPB];
}

// After k_place, starts[b] == end(b); list for bin b = [b ? starts[b-1] : 0, starts[b])
__global__ __launch_bounds__(256) void k_place(const int* __restrict__ src, const int* __restrict__ dst,
                                               const int* __restrict__ et, int* __restrict__ starts,
                                               int* __restrict__ esrc) {
  int e = blockIdx.x * 256 + threadIdx.x;
  if (e >= NE) return;
  int b = et[e] * NN + dst[e];
  int pos = atomicAdd(&starts[b], 1);
  esrc[pos] = src[e];
}

// ---------------- weight prep: fragment-ordered bf16 ----------------
// [m:4][p:COUT/64][kk:CIN/32][ct:4][l:64][j:8]; ki = kk*32+(l>>4)*4+(j&3)+16*(j>>2), c = p*64+ct*16+(l&15)
__global__ __launch_bounds__(256) void k_prepw(const float* __restrict__ Wid, const float* __restrict__ Wc,
                                               unsigned short* __restrict__ Wtf, int CIN_, int COUT_) {
  int i = blockIdx.x * 256 + threadIdx.x;
  if (i >= 4 * CIN_ * COUT_) return;
  int j = i & 7, lq = (i >> 3) & 63, ct = (i >> 9) & 3;
  int rest = i >> 11;
  int KK = CIN_ / 32, NP = COUT_ / 64;
  int kk = rest % KK; rest /= KK;
  int p = rest % NP; int m = rest / NP;
  int ki = kk * 32 + (lq >> 4) * 4 + (j & 3) + 16 * (j >> 2);
  int c = p * 64 + ct * 16 + (lq & 15);
  float wv = (m == 0) ? Wid[(size_t)ki * COUT_ + c] : Wc[(size_t)((m - 1) * CIN_ + ki) * COUT_ + c];
  Wtf[i] = f2b(wv);
}

// ---------------- gather-reduce aggregation (CSR) ----------------
// aggXb[t*nloc+nl][c] = bf16( dinv_dst * sum_{e in list(t, lo+nl)} dinv_src * h[src][c] )
template <int CIN, typename TIN>
__global__ __launch_bounds__(256) void k_agg(const int* __restrict__ starts, const int* __restrict__ esrc,
                                             const float* __restrict__ dinv, const TIN* __restrict__ h,
                                             unsigned short* __restrict__ aggXb, int lo, int nloc) {
  constexpr int TPB = (CIN == 32) ? 32 : 64;
  constexpr int V = CIN / TPB;  // 1 or 2
  const int idx = blockIdx.x * 256 + threadIdx.x;
  const int bl = idx / TPB;
  const int lane = idx % TPB;
  if (bl >= 3 * nloc) return;
  const int t = bl / nloc;
  const int bin = t * NN + lo + (bl - t * nloc);
  const int s = (bin == 0) ? 0 : starts[bin - 1];
  const int e2 = starts[bin];
  float acc[V];
#pragma unroll
  for (int j = 0; j < V; j++) acc[j] = 0.f;
  for (int i = s; i < e2; i++) {
    const int sn = esrc[i];
    const float dv = dinv[(size_t)t * NN + sn];
    if (dv == 0.f) continue;
    const TIN* hp = h + (size_t)sn * CIN + lane * V;
#pragma unroll
    for (int j = 0; j < V; j++) {
      float v;
      if constexpr (sizeof(TIN) == 2) v = b2f(((const unsigned short*)hp)[j]);
      else v = ((const float*)hp)[j];
      acc[j] = fmaf(v, dv, acc[j]);
    }
  }
  const float dvd = dinv[bin];
  unsigned short* op = aggXb + (size_t)bl * CIN + lane * V;
#pragma unroll
  for (int j = 0; j < V; j++) op[j] = f2b(acc[j] * dvd);
}

// ---------------- fused finish via bf16 MFMA ----------------
// One block per 64-node tile; all COUT panels looped in-block with A-frags in registers.
// run = relu(X@Wid+bid) + sum_k relu(aggXb_k@Wc_k+bc_k); parallel LDS epilogue.
template <int CIN, int COUT, bool INBF16, bool WRITEOUT, bool DOPOOL>
__global__ __launch_bounds__(256) void k_fin(
    const void* __restrict__ Xv, const unsigned short* __restrict__ aggXb,
    int lo, int nloc, const unsigned short* __restrict__ Wtf,
    const float* __restrict__ bid, const float* __restrict__ bc,
    unsigned short* __restrict__ outb, float* __restrict__ stats,
    float* __restrict__ pooled, const int* __restrict__ batch) {
  constexpr int NP = COUT / 64;
  constexpr int KK = CIN / 32;
  __shared__ float tile[64][65];
  __shared__ float sred[2][4][64];
  __shared__ int sbatch[64];
  const int ln0 = blockIdx.x * 64;
  const int n0 = lo + ln0;
  const int tid = threadIdx.x, w = tid >> 6, l = tid & 63, lr = l & 15, q = l >> 4;
  const int rA = w * 16 + lr;
  const int nA = n0 + rA;

  // ---- load ALL A fragments into registers (once; reused by every panel) ----
  short8b fa[4][KK];
#pragma unroll
  for (int m = 0; m < 4; m++) {
#pragma unroll
    for (int kk = 0; kk < KK; kk++) {
      union { ushort4 u4[2]; short8b v; } t;
      if (m > 0) {
        const unsigned short* ar = aggXb + ((size_t)(m - 1) * nloc + ln0 + rA) * CIN + kk * 32;
        t.u4[0] = *(const ushort4*)(ar + q * 4);
        t.u4[1] = *(const ushort4*)(ar + 16 + q * 4);
      } else if (INBF16) {
        const unsigned short* xr = (const unsigned short*)Xv + (size_t)nA * CIN + kk * 32;
        t.u4[0] = *(const ushort4*)(xr + q * 4);
        t.u4[1] = *(const ushort4*)(xr + 16 + q * 4);
      } else {
        const float* xr = (const float*)Xv + (size_t)nA * CIN + kk * 32;
        float4 v0 = *(const float4*)(xr + q * 4);
        float4 v1 = *(const float4*)(xr + 16 + q * 4);
        t.u4[0] = make_ushort4(f2b(v0.x), f2b(v0.y), f2b(v0.z), f2b(v0.w));
        t.u4[1] = make_ushort4(f2b(v1.x), f2b(v1.y), f2b(v1.z), f2b(v1.w));
      }
      fa[m][kk] = t.v;
    }
  }
  if (DOPOOL && tid < 64) sbatch[tid] = batch[n0 + tid];

#pragma unroll
  for (int p = 0; p < NP; p++) {
    const int c0 = p * 64;
    f32x4 run[4];
#pragma unroll
    for (int ct = 0; ct < 4; ct++) run[ct] = (f32x4){0.f, 0.f, 0.f, 0.f};
#pragma unroll
    for (int m = 0; m < 4; m++) {
      f32x4 acc[4];
#pragma unroll
      for (int ct = 0; ct < 4; ct++) acc[ct] = (f32x4){0.f, 0.f, 0.f, 0.f};
      const short8b* bfr = (const short8b*)(Wtf) + ((size_t)(m * NP + p) * KK) * 256;
#pragma unroll
      for (int kk = 0; kk < KK; kk++) {
        const short8b* bk = bfr + (size_t)kk * 256;
#pragma unroll
        for (int ct = 0; ct < 4; ct++)
          acc[ct] = __builtin_amdgcn_mfma_f32_16x16x32_bf16(fa[m][kk], bk[ct * 64 + l], acc[ct], 0, 0, 0);
      }
      const float* bp = (m == 0) ? bid : bc + (size_t)(m - 1) * COUT;
#pragma unroll
      for (int ct = 0; ct < 4; ct++) {
        float bb = bp[c0 + ct * 16 + lr];
#pragma unroll
        for (int j = 0; j < 4; j++) run[ct][j] += fmaxf(acc[ct][j] + bb, 0.f);
      }
    }

    // ---- stage tile: row = node-in-tile, col = channel-in-panel ----
#pragma unroll
    for (int ct = 0; ct < 4; ct++)
#pragma unroll
      for (int j = 0; j < 4; j++) tile[w * 16 + q * 4 + j][ct * 16 + lr] = run[ct][j];
    __syncthreads();

    if (WRITEOUT) {
      const int r = tid >> 2, cg = (tid & 3) * 16;
      ushort4 o[4];
#pragma unroll
      for (int g4 = 0; g4 < 4; g4++) {
        o[g4].x = f2b(tile[r][cg + g4 * 4 + 0]);
        o[g4].y = f2b(tile[r][cg + g4 * 4 + 1]);
        o[g4].z = f2b(tile[r][cg + g4 * 4 + 2]);
        o[g4].w = f2b(tile[r][cg + g4 * 4 + 3]);
      }
      ushort4* dst4 = (ushort4*)(outb + (size_t)(n0 + r) * COUT + c0 + cg);
#pragma unroll
      for (int g4 = 0; g4 < 4; g4++) dst4[g4] = o[g4];
    }
    {  // parallel stats + pool: thread = (rowgroup rg, col)
      const int col = tid & 63, rg = tid >> 6, r0 = rg * 16;
      float s = 0.f, ss = 0.f, gs = 0.f;
      int curg = DOPOOL ? sbatch[r0] : 0;
#pragma unroll
      for (int r = 0; r < 16; r++) {
        float v = tile[r0 + r][col];
        s += v; ss += v * v;
        if (DOPOOL) {
          int g = sbatch[r0 + r];
          if (g != curg) { atomAddF(&pooled[(size_t)curg * C2 + c0 + col], gs); gs = 0.f; curg = g; }
          gs += v;
        }
      }
      if (DOPOOL) atomAddF(&pooled[(size_t)curg * C2 + c0 + col], gs);
      sred[0][rg][col] = s;
      sred[1][rg][col] = ss;
    }
    __syncthreads();
    if (tid < 64) {
      float s4 = sred[0][0][tid] + sred[0][1][tid] + sred[0][2][tid] + sred[0][3][tid];
      float ss4 = sred[1][0][tid] + sred[1][1][tid] + sred[1][2][tid] + sred[1][3][tid];
      atomAddF(&stats[c0 + tid], s4);
      atomAddF(&stats[COUT + c0 + tid], ss4);
    }
  }
}

// ---------------- BN finalize -> per-channel scale/shift ----------------
__global__ __launch_bounds__(256) void k_bnfin(const float* __restrict__ stats, const float* __restrict__ gamma,
                                               const float* __restrict__ beta, float* __restrict__ sc,
                                               float* __restrict__ sh, int COUT) {
  int c = threadIdx.x;
  if (c < COUT) {
    const float invN = 1.f / (float)NN;
    float m = stats[c] * invN;
    float v = stats[COUT + c] * invN - m * m;
    float s = gamma[c] / sqrtf(v + 1e-5f);
    sc[c] = s;
    sh[c] = fmaf(-m, s, beta[c]);
  }
}

// ---------------- fold BN1 into out1 (bf16, in place) ----------------
__global__ __launch_bounds__(256) void k_bnfold(unsigned short* __restrict__ o, const float* __restrict__ sc,
                                                const float* __restrict__ sh) {
  size_t i8 = ((size_t)blockIdx.x * 256 + threadIdx.x) * 8;
  if (i8 >= (size_t)NN * C1) return;
  const int c = (int)(i8 & (C1 - 1));
  ushort4 a = *(ushort4*)(o + i8);
  ushort4 b = *(ushort4*)(o + i8 + 4);
  a.x = f2b(fmaf(b2f(a.x), sc[c + 0], sh[c + 0]));
  a.y = f2b(fmaf(b2f(a.y), sc[c + 1], sh[c + 1]));
  a.z = f2b(fmaf(b2f(a.z), sc[c + 2], sh[c + 2]));
  a.w = f2b(fmaf(b2f(a.w), sc[c + 3], sh[c + 3]));
  b.x = f2b(fmaf(b2f(b.x), sc[c + 4], sh[c + 4]));
  b.y = f2b(fmaf(b2f(b.y), sc[c + 5], sh[c + 5]));
  b.z = f2b(fmaf(b2f(b.z), sc[c + 6], sh[c + 6]));
  b.w = f2b(fmaf(b2f(b.w), sc[c + 7], sh[c + 7]));
  *(ushort4*)(o + i8) = a;
  *(ushort4*)(o + i8 + 4) = b;
}

// ---------------- MLP head: BN2 affine folded into pooled sums ----------------
__global__ __launch_bounds__(256) void k_mlp(const float* __restrict__ pooled, const float* __restrict__ counts,
                                             const float* __restrict__ sc2, const float* __restrict__ sh2,
                                             const float* __restrict__ Wf1, const float* __restrict__ bf1,
                                             const float* __restrict__ Wf2, const float* __restrict__ bf2,
                                             float* __restrict__ out) {
  __shared__ float feat[257];
  __shared__ float hid[256];
  const int g = blockIdx.x, t = threadIdx.x;
  const float cnt = counts[g];
  feat[t] = fmaf(sc2[t], pooled[(size_t)g * C2 + t], sh2[t] * cnt);
  if (t == 0) feat[256] = cnt * 0.025f;
  __syncthreads();
  float acc = bf1[t];
  for (int i = 0; i < 257; i++) acc = fmaf(feat[i], Wf1[(size_t)i * MLPH + t], acc);
  hid[t] = fmaxf(acc, 0.f);
  __syncthreads();
  if (t < NCLS) {
    float o = bf2[t];
    for (int j = 0; j < MLPH; j++) o = fmaf(hid[j], Wf2[(size_t)j * NCLS + t], o);
    out[(size_t)g * NCLS + t] = o;
  }
}

extern "C" void kernel_launch(void* const* d_in, const int* in_sizes, int n_in,
                              void* d_out, int out_size, void* d_ws, size_t ws_size,
                              hipStream_t stream) {
  const float* x = (const float*)d_in[0];
  const int* ei = (const int*)d_in[1];
  const int* et = (const int*)d_in[2];
  const int* batch = (const int*)d_in[3];
  const float* Wc0 = (const float*)d_in[4];
  const float* bc0 = (const float*)d_in[5];
  const float* Wid0 = (const float*)d_in[6];
  const float* bid0 = (const float*)d_in[7];
  const float* gm0 = (const float*)d_in[8];
  const float* bt0 = (const float*)d_in[9];
  const float* Wc1 = (const float*)d_in[10];
  const float* bc1 = (const float*)d_in[11];
  const float* Wid1 = (const float*)d_in[12];
  const float* bid1 = (const float*)d_in[13];
  const float* gm1 = (const float*)d_in[14];
  const float* bt1 = (const float*)d_in[15];
  const float* Wf1 = (const float*)d_in[16];
  const float* bf1 = (const float*)d_in[17];
  const float* Wf2 = (const float*)d_in[18];
  const float* bf2 = (const float*)d_in[19];
  const int* srcI = ei;
  const int* dstI = ei + NE;
  float* outp = (float*)d_out;

  char* ws = (char*)d_ws;
  size_t off = 0;
  auto take = [&](size_t bytes) -> char* {
    char* p = ws + off;
    off = (off + bytes + 255) & ~(size_t)255;
    return p;
  };
  float* dinv = (float*)take((size_t)NB * 4);
  int* cnt = (int*)take((size_t)NB * 4);
  int* starts = (int*)take((size_t)NB * 4);
  int* bsum = (int*)take((size_t)SCAN_NBLK * 4);
  int* esrc = (int*)take((size_t)NE * 4);
  float* stats1 = (float*)take(2 * C1 * 4);
  float* stats2 = (float*)take(2 * C2 * 4);
  float* sc1 = (float*)take(C1 * 4);
  float* sh1 = (float*)take(C1 * 4);
  float* sc2 = (float*)take(C2 * 4);
  float* sh2 = (float*)take(C2 * 4);
  float* counts = (float*)take((size_t)NG * 4);
  float* pooled = (float*)take((size_t)NG * C2 * 4);
  unsigned short* Wtf1 = (unsigned short*)take((size_t)4 * C0 * C1 * 2);
  unsigned short* Wtf2 = (unsigned short*)take((size_t)4 * C1 * C2 * 2);
  unsigned short* out1 = (unsigned short*)take((size_t)NN * C1 * 2);
  const size_t min_agg = (size_t)3 * 64 * C1 * 2;
  if (off + min_agg > ws_size) {
    k_fill<<<(out_size + 255) / 256, 256, 0, stream>>>(outp, out_size, 100.f);
    return;
  }
  unsigned short* aggXb = (unsigned short*)(ws + off);
  const size_t left = ws_size - off;
  long long ch1 = (long long)(left / ((size_t)3 * C0 * 2)) & ~63LL;
  long long ch2 = (long long)(left / ((size_t)3 * C1 * 2)) & ~63LL;
  if (ch1 > NN) ch1 = NN;
  if (ch2 > NN) ch2 = NN;

  dim3 blk(256);
  hipMemsetAsync(cnt, 0, (size_t)NB * 4, stream);
  hipMemsetAsync(stats1, 0, 2 * C1 * 4, stream);
  hipMemsetAsync(stats2, 0, 2 * C2 * 4, stream);
  hipMemsetAsync(counts, 0, (size_t)NG * 4, stream);
  hipMemsetAsync(pooled, 0, (size_t)NG * C2 * 4, stream);

  // ---- CSR build (histogram doubles as degree) ----
  k_hist<<<(NE + 255) / 256, blk, 0, stream>>>(dstI, et, cnt);
  k_dinvI<<<(NB + 255) / 256, blk, 0, stream>>>(cnt, dinv);
  k_counts<<<(NN + 255) / 256, blk, 0, stream>>>(batch, counts);
  k_scan1<<<SCAN_NBLK, blk, 0, stream>>>(cnt, starts, bsum);
  k_scan2<<<1, 64, 0, stream>>>(bsum);
  k_scan3<<<(NB + 255) / 256, blk, 0, stream>>>(starts, bsum);
  k_place<<<(NE + 255) / 256, blk, 0, stream>>>(srcI, dstI, et, starts, esrc);

  k_prepw<<<(4 * C0 * C1 + 255) / 256, blk, 0, stream>>>(Wid0, Wc0, Wtf1, C0, C1);
  k_prepw<<<(4 * C1 * C2 + 255) / 256, blk, 0, stream>>>(Wid1, Wc1, Wtf2, C1, C2);

  // ---- layer 1: x (f32, 32ch) -> out1 bf16 pre-BN (128ch) + stats1 ----
  for (long long lo = 0; lo < NN; lo += ch1) {
    const int nloc = (int)((NN - lo < ch1) ? (NN - lo) : ch1);
    k_agg<C0, float><<<(3 * nloc * 32 + 255) / 256, blk, 0, stream>>>(starts, esrc, dinv, x, aggXb,
                                                                      (int)lo, nloc);
    k_fin<C0, C1, false, true, false><<<nloc / 64, blk, 0, stream>>>(
        x, aggXb, (int)lo, nloc, Wtf1, bid0, bc0, out1, stats1, nullptr, nullptr);
  }
  k_bnfin<<<1, blk, 0, stream>>>(stats1, gm0, bt0, sc1, sh1, C1);
  k_bnfold<<<(int)(((size_t)NN * C1 / 8 + 255) / 256), blk, 0, stream>>>(out1, sc1, sh1);

  // ---- layer 2: out1 bf16 (BN1 folded) -> stats2 + pre-BN pooled ----
  for (long long lo = 0; lo < NN; lo += ch2) {
    const int nloc = (int)((NN - lo < ch2) ? (NN - lo) : ch2);
    k_agg<C1, unsigned short><<<(3 * nloc * 64 + 255) / 256, blk, 0, stream>>>(starts, esrc, dinv, out1,
                                                                               aggXb, (int)lo, nloc);
    k_fin<C1, C2, true, false, true><<<nloc / 64, blk, 0, stream>>>(
        out1, aggXb, (int)lo, nloc, Wtf2, bid1, bc1, nullptr, stats2, pooled, batch);
  }
  k_bnfin<<<1, blk, 0, stream>>>(stats2, gm1, bt1, sc2, sh2, C2);

  // ---- MLP head ----
  k_mlp<<<NG, blk, 0, stream>>>(pooled, counts, sc2, sh2, Wf1, bf1, Wf2, bf2, outp);
}

// Round 7
// 945.975 us; speedup vs baseline: 1.0828x; 1.0828x over previous
//
#include <hip/hip_runtime.h>
#include <cstdint>
#include <cstddef>

#define NN 200000
#define NE 600000
#define NG 8192
#define C0 32
#define C1 128
#define C2 256
#define MLPH 256
#define NCLS 10
#define NB (3 * NN)
#define SCAN_BPB 1024
#define SCAN_NBLK ((NB + SCAN_BPB - 1) / SCAN_BPB)

typedef __attribute__((ext_vector_type(8))) short short8b;  // 8 bf16 = 4 VGPR
typedef __attribute__((ext_vector_type(4))) float f32x4;

__device__ __forceinline__ void atomAddF(float* p, float v) { unsafeAtomicAdd(p, v); }

__device__ __forceinline__ float b2f(unsigned short u) {
  union { unsigned u; float f; } v; v.u = ((unsigned)u) << 16; return v.f;
}
__device__ __forceinline__ unsigned short f2b(float f) {  // RNE
  union { float f; unsigned u; } v; v.f = f;
  return (unsigned short)((v.u + 0x7FFF + ((v.u >> 16) & 1)) >> 16);
}

// ---------------- small utility kernels ----------------
__global__ __launch_bounds__(256) void k_fill(float* __restrict__ p, int n, float v) {
  int i = blockIdx.x * 256 + threadIdx.x;
  if (i < n) p[i] = v;
}

__global__ __launch_bounds__(256) void k_counts(const int* __restrict__ batch, float* __restrict__ counts) {
  int n = blockIdx.x * 256 + threadIdx.x;
  if (n < NN) atomAddF(&counts[batch[n]], 1.f);
}

// ---------------- CSR build: histogram (= degree), scan, place ----------------
__global__ __launch_bounds__(256) void k_hist(const int* __restrict__ dst, const int* __restrict__ et,
                                              int* __restrict__ cnt) {
  int e = blockIdx.x * 256 + threadIdx.x;
  if (e < NE) atomicAdd(&cnt[et[e] * NN + dst[e]], 1);
}

__global__ __launch_bounds__(256) void k_dinvI(const int* __restrict__ cnt, float* __restrict__ dinv) {
  int i = blockIdx.x * 256 + threadIdx.x;
  if (i < NB) { int c = cnt[i]; dinv[i] = (c > 0) ? 1.f / sqrtf((float)c) : 0.f; }
}

__global__ __launch_bounds__(256) void k_scan1(const int* __restrict__ cnt, int* __restrict__ starts,
                                               int* __restrict__ bsum) {
  __shared__ int sh[256];
  const int b0 = blockIdx.x * SCAN_BPB + threadIdx.x * 4;
  int v[4]; int tot = 0;
#pragma unroll
  for (int j = 0; j < 4; j++) {
    int b = b0 + j;
    v[j] = tot;
    tot += (b < NB) ? cnt[b] : 0;
  }
  sh[threadIdx.x] = tot;
  __syncthreads();
  for (int ofs = 1; ofs < 256; ofs <<= 1) {
    int add = (threadIdx.x >= ofs) ? sh[threadIdx.x - ofs] : 0;
    __syncthreads();
    sh[threadIdx.x] += add;
    __syncthreads();
  }
  const int excl = (threadIdx.x == 0) ? 0 : sh[threadIdx.x - 1];
#pragma unroll
  for (int j = 0; j < 4; j++) {
    int b = b0 + j;
    if (b < NB) starts[b] = excl + v[j];
  }
  if (threadIdx.x == 255) bsum[blockIdx.x] = sh[255];
}

__global__ void k_scan2(int* __restrict__ bsum) {
  if (threadIdx.x == 0) {
    int acc = 0;
    for (int i = 0; i < SCAN_NBLK; i++) { int t = bsum[i]; bsum[i] = acc; acc += t; }
  }
}

__global__ __launch_bounds__(256) void k_scan3(int* __restrict__ starts, const int* __restrict__ bsum) {
  int b = blockIdx.x * 256 + threadIdx.x;
  if (b < NB) starts[b] += bsum[b / SCAN_BPB];
}

// After k_place, starts[b] == end(b); list for bin b = [b ? starts[b-1] : 0, starts[b])
__global__ __launch_bounds__(256) void k_place(const int* __restrict__ src, const int* __restrict__ dst,
                                               const int* __restrict__ et, int* __restrict__ starts,
                                               int* __restrict__ esrc) {
  int e = blockIdx.x * 256 + threadIdx.x;
  if (e >= NE) return;
  int b = et[e] * NN + dst[e];
  int pos = atomicAdd(&starts[b], 1);
  esrc[pos] = src[e];
}

// ---------------- weight prep: fragment-ordered bf16 ----------------
// [m:4][p:COUT/64][kk:CIN/32][ct:4][l:64][j:8]; ki = kk*32+(l>>4)*4+(j&3)+16*(j>>2), c = p*64+ct*16+(l&15)
__global__ __launch_bounds__(256) void k_prepw(const float* __restrict__ Wid, const float* __restrict__ Wc,
                                               unsigned short* __restrict__ Wtf, int CIN_, int COUT_) {
  int i = blockIdx.x * 256 + threadIdx.x;
  if (i >= 4 * CIN_ * COUT_) return;
  int j = i & 7, lq = (i >> 3) & 63, ct = (i >> 9) & 3;
  int rest = i >> 11;
  int KK = CIN_ / 32, NP = COUT_ / 64;
  int kk = rest % KK; rest /= KK;
  int p = rest % NP; int m = rest / NP;
  int ki = kk * 32 + (lq >> 4) * 4 + (j & 3) + 16 * (j >> 2);
  int c = p * 64 + ct * 16 + (lq & 15);
  float wv = (m == 0) ? Wid[(size_t)ki * COUT_ + c] : Wc[(size_t)((m - 1) * CIN_ + ki) * COUT_ + c];
  Wtf[i] = f2b(wv);
}

// ---------------- gather-reduce aggregation (CSR) ----------------
// aggXb[t*nloc+nl][c] = bf16( dinv_dst * sum_{e in list(t, lo+nl)} dinv_src * h[src][c] )
template <int CIN, typename TIN>
__global__ __launch_bounds__(256) void k_agg(const int* __restrict__ starts, const int* __restrict__ esrc,
                                             const float* __restrict__ dinv, const TIN* __restrict__ h,
                                             unsigned short* __restrict__ aggXb, int lo, int nloc) {
  constexpr int TPB = (CIN == 32) ? 32 : 64;
  constexpr int V = CIN / TPB;  // 1 or 2
  const int idx = blockIdx.x * 256 + threadIdx.x;
  const int bl = idx / TPB;
  const int lane = idx % TPB;
  if (bl >= 3 * nloc) return;
  const int t = bl / nloc;
  const int bin = t * NN + lo + (bl - t * nloc);
  const int s = (bin == 0) ? 0 : starts[bin - 1];
  const int e2 = starts[bin];
  float acc[V];
#pragma unroll
  for (int j = 0; j < V; j++) acc[j] = 0.f;
  for (int i = s; i < e2; i++) {
    const int sn = esrc[i];
    const float dv = dinv[(size_t)t * NN + sn];
    if (dv == 0.f) continue;
    const TIN* hp = h + (size_t)sn * CIN + lane * V;
#pragma unroll
    for (int j = 0; j < V; j++) {
      float v;
      if constexpr (sizeof(TIN) == 2) v = b2f(((const unsigned short*)hp)[j]);
      else v = ((const float*)hp)[j];
      acc[j] = fmaf(v, dv, acc[j]);
    }
  }
  const float dvd = dinv[bin];
  unsigned short* op = aggXb + (size_t)bl * CIN + lane * V;
#pragma unroll
  for (int j = 0; j < V; j++) op[j] = f2b(acc[j] * dvd);
}

// ---------------- fused finish via bf16 MFMA ----------------
// 1D grid, XCD-swizzled: all COUT-panels of one 64-node tile land on the SAME XCD
// (xcd = tile % 8 heuristic) so the A-tile (X + aggXb rows) is fetched from HBM once
// and re-read from that XCD's L2 by the other panels.
// run = relu(X@Wid+bid) + sum_k relu(aggXb_k@Wc_k+bc_k); parallel LDS epilogue.
template <int CIN, int COUT, bool INBF16, bool WRITEOUT, bool DOPOOL>
__global__ __launch_bounds__(256) void k_fin(
    const void* __restrict__ Xv, const unsigned short* __restrict__ aggXb,
    int lo, int nloc, int nt, const unsigned short* __restrict__ Wtf,
    const float* __restrict__ bid, const float* __restrict__ bc,
    unsigned short* __restrict__ outb, float* __restrict__ stats,
    float* __restrict__ pooled, const int* __restrict__ batch) {
  constexpr int NP = COUT / 64;
  constexpr int KK = CIN / 32;
  __shared__ float tile[64][65];
  __shared__ float sred[2][4][64];
  __shared__ int sbatch[64];
  // ---- XCD swizzle decode: i = xr8 + 8*(ti*NP + p) ----
  const int i = blockIdx.x;
  const int xr8 = i & 7;
  const int xq = i >> 3;
  const int p = xq % NP;
  const int ti = xq / NP;
  const int tileIdx = ti * 8 + xr8;
  if (tileIdx >= nt) return;
  const int ln0 = tileIdx * 64;
  const int n0 = lo + ln0;
  const int c0 = p * 64;
  const int tid = threadIdx.x, w = tid >> 6, l = tid & 63, lr = l & 15, lq = l >> 4;
  const int rA = w * 16 + lr;
  const int nA = n0 + rA;

  f32x4 run[4];
#pragma unroll
  for (int ct = 0; ct < 4; ct++) run[ct] = (f32x4){0.f, 0.f, 0.f, 0.f};
  if (DOPOOL && tid < 64) sbatch[tid] = batch[n0 + tid];

#pragma unroll
  for (int m = 0; m < 4; m++) {
    f32x4 acc[4];
#pragma unroll
    for (int ct = 0; ct < 4; ct++) acc[ct] = (f32x4){0.f, 0.f, 0.f, 0.f};
    const unsigned short* ar = (m > 0) ? aggXb + ((size_t)(m - 1) * nloc + ln0 + rA) * CIN : nullptr;
    const short8b* bfr = (const short8b*)(Wtf) + ((size_t)(m * NP + p) * KK) * 256;
#pragma unroll
    for (int kk = 0; kk < KK; kk++) {
      union { ushort4 u4[2]; short8b v; } fa;
      if (m > 0) {
        fa.u4[0] = *(const ushort4*)(ar + kk * 32 + lq * 4);
        fa.u4[1] = *(const ushort4*)(ar + kk * 32 + 16 + lq * 4);
      } else if (INBF16) {
        const unsigned short* xr = (const unsigned short*)Xv + (size_t)nA * CIN + kk * 32;
        fa.u4[0] = *(const ushort4*)(xr + lq * 4);
        fa.u4[1] = *(const ushort4*)(xr + 16 + lq * 4);
      } else {
        const float* xr = (const float*)Xv + (size_t)nA * CIN + kk * 32;
        float4 v0 = *(const float4*)(xr + lq * 4);
        float4 v1 = *(const float4*)(xr + 16 + lq * 4);
        fa.u4[0] = make_ushort4(f2b(v0.x), f2b(v0.y), f2b(v0.z), f2b(v0.w));
        fa.u4[1] = make_ushort4(f2b(v1.x), f2b(v1.y), f2b(v1.z), f2b(v1.w));
      }
      const short8b* bk = bfr + (size_t)kk * 256;
#pragma unroll
      for (int ct = 0; ct < 4; ct++)
        acc[ct] = __builtin_amdgcn_mfma_f32_16x16x32_bf16(fa.v, bk[ct * 64 + l], acc[ct], 0, 0, 0);
    }
    const float* bp = (m == 0) ? bid : bc + (size_t)(m - 1) * COUT;
#pragma unroll
    for (int ct = 0; ct < 4; ct++) {
      float bb = bp[c0 + ct * 16 + lr];
#pragma unroll
      for (int j = 0; j < 4; j++) run[ct][j] += fmaxf(acc[ct][j] + bb, 0.f);
    }
  }

  // ---- stage tile: row = node-in-tile, col = channel-in-panel ----
#pragma unroll
  for (int ct = 0; ct < 4; ct++)
#pragma unroll
    for (int j = 0; j < 4; j++) tile[w * 16 + lq * 4 + j][ct * 16 + lr] = run[ct][j];
  __syncthreads();

  if (WRITEOUT) {
    const int r = tid >> 2, cg = (tid & 3) * 16;
    ushort4 o[4];
#pragma unroll
    for (int g4 = 0; g4 < 4; g4++) {
      o[g4].x = f2b(tile[r][cg + g4 * 4 + 0]);
      o[g4].y = f2b(tile[r][cg + g4 * 4 + 1]);
      o[g4].z = f2b(tile[r][cg + g4 * 4 + 2]);
      o[g4].w = f2b(tile[r][cg + g4 * 4 + 3]);
    }
    ushort4* dst4 = (ushort4*)(outb + (size_t)(n0 + r) * COUT + c0 + cg);
#pragma unroll
    for (int g4 = 0; g4 < 4; g4++) dst4[g4] = o[g4];
  }
  {  // parallel stats + pool: thread = (rowgroup rg, col)
    const int col = tid & 63, rg = tid >> 6, r0 = rg * 16;
    float s = 0.f, ss = 0.f, gs = 0.f;
    int curg = DOPOOL ? sbatch[r0] : 0;
#pragma unroll
    for (int r = 0; r < 16; r++) {
      float v = tile[r0 + r][col];
      s += v; ss += v * v;
      if (DOPOOL) {
        int g = sbatch[r0 + r];
        if (g != curg) { atomAddF(&pooled[(size_t)curg * C2 + c0 + col], gs); gs = 0.f; curg = g; }
        gs += v;
      }
    }
    if (DOPOOL) atomAddF(&pooled[(size_t)curg * C2 + c0 + col], gs);
    sred[0][rg][col] = s;
    sred[1][rg][col] = ss;
  }
  __syncthreads();
  if (tid < 64) {
    float s4 = sred[0][0][tid] + sred[0][1][tid] + sred[0][2][tid] + sred[0][3][tid];
    float ss4 = sred[1][0][tid] + sred[1][1][tid] + sred[1][2][tid] + sred[1][3][tid];
    atomAddF(&stats[c0 + tid], s4);
    atomAddF(&stats[COUT + c0 + tid], ss4);
  }
}

// ---------------- BN finalize -> per-channel scale/shift ----------------
__global__ __launch_bounds__(256) void k_bnfin(const float* __restrict__ stats, const float* __restrict__ gamma,
                                               const float* __restrict__ beta, float* __restrict__ sc,
                                               float* __restrict__ sh, int COUT) {
  int c = threadIdx.x;
  if (c < COUT) {
    const float invN = 1.f / (float)NN;
    float m = stats[c] * invN;
    float v = stats[COUT + c] * invN - m * m;
    float s = gamma[c] / sqrtf(v + 1e-5f);
    sc[c] = s;
    sh[c] = fmaf(-m, s, beta[c]);
  }
}

// ---------------- fold BN1 into out1 (bf16, in place) ----------------
__global__ __launch_bounds__(256) void k_bnfold(unsigned short* __restrict__ o, const float* __restrict__ sc,
                                                const float* __restrict__ sh) {
  size_t i8 = ((size_t)blockIdx.x * 256 + threadIdx.x) * 8;
  if (i8 >= (size_t)NN * C1) return;
  const int c = (int)(i8 & (C1 - 1));
  ushort4 a = *(ushort4*)(o + i8);
  ushort4 b = *(ushort4*)(o + i8 + 4);
  a.x = f2b(fmaf(b2f(a.x), sc[c + 0], sh[c + 0]));
  a.y = f2b(fmaf(b2f(a.y), sc[c + 1], sh[c + 1]));
  a.z = f2b(fmaf(b2f(a.z), sc[c + 2], sh[c + 2]));
  a.w = f2b(fmaf(b2f(a.w), sc[c + 3], sh[c + 3]));
  b.x = f2b(fmaf(b2f(b.x), sc[c + 4], sh[c + 4]));
  b.y = f2b(fmaf(b2f(b.y), sc[c + 5], sh[c + 5]));
  b.z = f2b(fmaf(b2f(b.z), sc[c + 6], sh[c + 6]));
  b.w = f2b(fmaf(b2f(b.w), sc[c + 7], sh[c + 7]));
  *(ushort4*)(o + i8) = a;
  *(ushort4*)(o + i8 + 4) = b;
}

// ---------------- MLP head: BN2 affine folded into pooled sums ----------------
__global__ __launch_bounds__(256) void k_mlp(const float* __restrict__ pooled, const float* __restrict__ counts,
                                             const float* __restrict__ sc2, const float* __restrict__ sh2,
                                             const float* __restrict__ Wf1, const float* __restrict__ bf1,
                                             const float* __restrict__ Wf2, const float* __restrict__ bf2,
                                             float* __restrict__ out) {
  __shared__ float feat[257];
  __shared__ float hid[256];
  const int g = blockIdx.x, t = threadIdx.x;
  const float cnt = counts[g];
  feat[t] = fmaf(sc2[t], pooled[(size_t)g * C2 + t], sh2[t] * cnt);
  if (t == 0) feat[256] = cnt * 0.025f;
  __syncthreads();
  float acc = bf1[t];
  for (int i = 0; i < 257; i++) acc = fmaf(feat[i], Wf1[(size_t)i * MLPH + t], acc);
  hid[t] = fmaxf(acc, 0.f);
  __syncthreads();
  if (t < NCLS) {
    float o = bf2[t];
    for (int j = 0; j < MLPH; j++) o = fmaf(hid[j], Wf2[(size_t)j * NCLS + t], o);
    out[(size_t)g * NCLS + t] = o;
  }
}

extern "C" void kernel_launch(void* const* d_in, const int* in_sizes, int n_in,
                              void* d_out, int out_size, void* d_ws, size_t ws_size,
                              hipStream_t stream) {
  const float* x = (const float*)d_in[0];
  const int* ei = (const int*)d_in[1];
  const int* et = (const int*)d_in[2];
  const int* batch = (const int*)d_in[3];
  const float* Wc0 = (const float*)d_in[4];
  const float* bc0 = (const float*)d_in[5];
  const float* Wid0 = (const float*)d_in[6];
  const float* bid0 = (const float*)d_in[7];
  const float* gm0 = (const float*)d_in[8];
  const float* bt0 = (const float*)d_in[9];
  const float* Wc1 = (const float*)d_in[10];
  const float* bc1 = (const float*)d_in[11];
  const float* Wid1 = (const float*)d_in[12];
  const float* bid1 = (const float*)d_in[13];
  const float* gm1 = (const float*)d_in[14];
  const float* bt1 = (const float*)d_in[15];
  const float* Wf1 = (const float*)d_in[16];
  const float* bf1 = (const float*)d_in[17];
  const float* Wf2 = (const float*)d_in[18];
  const float* bf2 = (const float*)d_in[19];
  const int* srcI = ei;
  const int* dstI = ei + NE;
  float* outp = (float*)d_out;

  char* ws = (char*)d_ws;
  size_t off = 0;
  auto take = [&](size_t bytes) -> char* {
    char* p = ws + off;
    off = (off + bytes + 255) & ~(size_t)255;
    return p;
  };
  float* dinv = (float*)take((size_t)NB * 4);
  int* cnt = (int*)take((size_t)NB * 4);
  int* starts = (int*)take((size_t)NB * 4);
  int* bsum = (int*)take((size_t)SCAN_NBLK * 4);
  int* esrc = (int*)take((size_t)NE * 4);
  float* stats1 = (float*)take(2 * C1 * 4);
  float* stats2 = (float*)take(2 * C2 * 4);
  float* sc1 = (float*)take(C1 * 4);
  float* sh1 = (float*)take(C1 * 4);
  float* sc2 = (float*)take(C2 * 4);
  float* sh2 = (float*)take(C2 * 4);
  float* counts = (float*)take((size_t)NG * 4);
  float* pooled = (float*)take((size_t)NG * C2 * 4);
  unsigned short* Wtf1 = (unsigned short*)take((size_t)4 * C0 * C1 * 2);
  unsigned short* Wtf2 = (unsigned short*)take((size_t)4 * C1 * C2 * 2);
  unsigned short* out1 = (unsigned short*)take((size_t)NN * C1 * 2);
  const size_t min_agg = (size_t)3 * 64 * C1 * 2;
  if (off + min_agg > ws_size) {
    k_fill<<<(out_size + 255) / 256, 256, 0, stream>>>(outp, out_size, 100.f);
    return;
  }
  unsigned short* aggXb = (unsigned short*)(ws + off);
  const size_t left = ws_size - off;
  long long ch1 = (long long)(left / ((size_t)3 * C0 * 2)) & ~63LL;
  long long ch2 = (long long)(left / ((size_t)3 * C1 * 2)) & ~63LL;
  if (ch1 > NN) ch1 = NN;
  if (ch2 > NN) ch2 = NN;

  dim3 blk(256);
  hipMemsetAsync(cnt, 0, (size_t)NB * 4, stream);
  hipMemsetAsync(stats1, 0, 2 * C1 * 4, stream);
  hipMemsetAsync(stats2, 0, 2 * C2 * 4, stream);
  hipMemsetAsync(counts, 0, (size_t)NG * 4, stream);
  hipMemsetAsync(pooled, 0, (size_t)NG * C2 * 4, stream);

  // ---- CSR build (histogram doubles as degree) ----
  k_hist<<<(NE + 255) / 256, blk, 0, stream>>>(dstI, et, cnt);
  k_dinvI<<<(NB + 255) / 256, blk, 0, stream>>>(cnt, dinv);
  k_counts<<<(NN + 255) / 256, blk, 0, stream>>>(batch, counts);
  k_scan1<<<SCAN_NBLK, blk, 0, stream>>>(cnt, starts, bsum);
  k_scan2<<<1, 64, 0, stream>>>(bsum);
  k_scan3<<<(NB + 255) / 256, blk, 0, stream>>>(starts, bsum);
  k_place<<<(NE + 255) / 256, blk, 0, stream>>>(srcI, dstI, et, starts, esrc);

  k_prepw<<<(4 * C0 * C1 + 255) / 256, blk, 0, stream>>>(Wid0, Wc0, Wtf1, C0, C1);
  k_prepw<<<(4 * C1 * C2 + 255) / 256, blk, 0, stream>>>(Wid1, Wc1, Wtf2, C1, C2);

  // ---- layer 1: x (f32, 32ch) -> out1 bf16 pre-BN (128ch) + stats1 ----
  for (long long lo = 0; lo < NN; lo += ch1) {
    const int nloc = (int)((NN - lo < ch1) ? (NN - lo) : ch1);
    const int nt = nloc / 64;
    const int nt8 = (nt + 7) & ~7;
    k_agg<C0, float><<<(3 * nloc * 32 + 255) / 256, blk, 0, stream>>>(starts, esrc, dinv, x, aggXb,
                                                                      (int)lo, nloc);
    k_fin<C0, C1, false, true, false><<<nt8 * (C1 / 64), blk, 0, stream>>>(
        x, aggXb, (int)lo, nloc, nt, Wtf1, bid0, bc0, out1, stats1, nullptr, nullptr);
  }
  k_bnfin<<<1, blk, 0, stream>>>(stats1, gm0, bt0, sc1, sh1, C1);
  k_bnfold<<<(int)(((size_t)NN * C1 / 8 + 255) / 256), blk, 0, stream>>>(out1, sc1, sh1);

  // ---- layer 2: out1 bf16 (BN1 folded) -> stats2 + pre-BN pooled ----
  for (long long lo = 0; lo < NN; lo += ch2) {
    const int nloc = (int)((NN - lo < ch2) ? (NN - lo) : ch2);
    const int nt = nloc / 64;
    const int nt8 = (nt + 7) & ~7;
    k_agg<C1, unsigned short><<<(3 * nloc * 64 + 255) / 256, blk, 0, stream>>>(starts, esrc, dinv, out1,
                                                                               aggXb, (int)lo, nloc);
    k_fin<C1, C2, true, false, true><<<nt8 * (C2 / 64), blk, 0, stream>>>(
        out1, aggXb, (int)lo, nloc, nt, Wtf2, bid1, bc1, nullptr, stats2, pooled, batch);
  }
  k_bnfin<<<1, blk, 0, stream>>>(stats2, gm1, bt1, sc2, sh2, C2);

  // ---- MLP head ----
  k_mlp<<<NG, blk, 0, stream>>>(pooled, counts, sc2, sh2, Wf1, bf1, Wf2, bf2, outp);
}

// Round 8
// 798.551 us; speedup vs baseline: 1.2827x; 1.1846x over previous
//
#include <hip/hip_runtime.h>
#include <cstdint>
#include <cstddef>

#define NN 200000
#define NE 600000
#define NG 8192
#define C0 32
#define C1 128
#define C2 256
#define MLPH 256
#define NCLS 10
#define NB (3 * NN)
#define SCAN_BPB 1024
#define SCAN_NBLK ((NB + SCAN_BPB - 1) / SCAN_BPB)
#define NREP 8  // stats atomic replication

typedef __attribute__((ext_vector_type(8))) short short8b;  // 8 bf16 = 4 VGPR
typedef __attribute__((ext_vector_type(4))) float f32x4;

__device__ __forceinline__ void atomAddF(float* p, float v) { unsafeAtomicAdd(p, v); }

__device__ __forceinline__ float b2f(unsigned short u) {
  union { unsigned u; float f; } v; v.u = ((unsigned)u) << 16; return v.f;
}
__device__ __forceinline__ unsigned short f2b(float f) {  // RNE
  union { float f; unsigned u; } v; v.f = f;
  return (unsigned short)((v.u + 0x7FFF + ((v.u >> 16) & 1)) >> 16);
}

// ---------------- small utility kernels ----------------
__global__ __launch_bounds__(256) void k_fill(float* __restrict__ p, int n, float v) {
  int i = blockIdx.x * 256 + threadIdx.x;
  if (i < n) p[i] = v;
}

__global__ __launch_bounds__(256) void k_counts(const int* __restrict__ batch, float* __restrict__ counts) {
  int n = blockIdx.x * 256 + threadIdx.x;
  if (n < NN) atomAddF(&counts[batch[n]], 1.f);
}

// ---------------- CSR build: histogram (= degree), scan, place ----------------
__global__ __launch_bounds__(256) void k_hist(const int* __restrict__ dst, const int* __restrict__ et,
                                              int* __restrict__ cnt) {
  int e = blockIdx.x * 256 + threadIdx.x;
  if (e < NE) atomicAdd(&cnt[et[e] * NN + dst[e]], 1);
}

__global__ __launch_bounds__(256) void k_dinvI(const int* __restrict__ cnt, float* __restrict__ dinv) {
  int i = blockIdx.x * 256 + threadIdx.x;
  if (i < NB) { int c = cnt[i]; dinv[i] = (c > 0) ? 1.f / sqrtf((float)c) : 0.f; }
}

__global__ __launch_bounds__(256) void k_scan1(const int* __restrict__ cnt, int* __restrict__ starts,
                                               int* __restrict__ bsum) {
  __shared__ int sh[256];
  const int b0 = blockIdx.x * SCAN_BPB + threadIdx.x * 4;
  int v[4]; int tot = 0;
#pragma unroll
  for (int j = 0; j < 4; j++) {
    int b = b0 + j;
    v[j] = tot;
    tot += (b < NB) ? cnt[b] : 0;
  }
  sh[threadIdx.x] = tot;
  __syncthreads();
  for (int ofs = 1; ofs < 256; ofs <<= 1) {
    int add = (threadIdx.x >= ofs) ? sh[threadIdx.x - ofs] : 0;
    __syncthreads();
    sh[threadIdx.x] += add;
    __syncthreads();
  }
  const int excl = (threadIdx.x == 0) ? 0 : sh[threadIdx.x - 1];
#pragma unroll
  for (int j = 0; j < 4; j++) {
    int b = b0 + j;
    if (b < NB) starts[b] = excl + v[j];
  }
  if (threadIdx.x == 255) bsum[blockIdx.x] = sh[255];
}

__global__ void k_scan2(int* __restrict__ bsum) {
  if (threadIdx.x == 0) {
    int acc = 0;
    for (int i = 0; i < SCAN_NBLK; i++) { int t = bsum[i]; bsum[i] = acc; acc += t; }
  }
}

__global__ __launch_bounds__(256) void k_scan3(int* __restrict__ starts, const int* __restrict__ bsum) {
  int b = blockIdx.x * 256 + threadIdx.x;
  if (b < NB) starts[b] += bsum[b / SCAN_BPB];
}

// After k_place, starts[b] == end(b); list for bin b = [b ? starts[b-1] : 0, starts[b])
__global__ __launch_bounds__(256) void k_place(const int* __restrict__ src, const int* __restrict__ dst,
                                               const int* __restrict__ et, int* __restrict__ starts,
                                               int* __restrict__ esrc) {
  int e = blockIdx.x * 256 + threadIdx.x;
  if (e >= NE) return;
  int b = et[e] * NN + dst[e];
  int pos = atomicAdd(&starts[b], 1);
  esrc[pos] = src[e];
}

// ---------------- weight prep: fragment-ordered bf16 ----------------
// [m:4][p:COUT/64][kk:CIN/32][ct:4][l:64][j:8]; ki = kk*32+(l>>4)*4+(j&3)+16*(j>>2), c = p*64+ct*16+(l&15)
__global__ __launch_bounds__(256) void k_prepw(const float* __restrict__ Wid, const float* __restrict__ Wc,
                                               unsigned short* __restrict__ Wtf, int CIN_, int COUT_) {
  int i = blockIdx.x * 256 + threadIdx.x;
  if (i >= 4 * CIN_ * COUT_) return;
  int j = i & 7, lq = (i >> 3) & 63, ct = (i >> 9) & 3;
  int rest = i >> 11;
  int KK = CIN_ / 32, NP = COUT_ / 64;
  int kk = rest % KK; rest /= KK;
  int p = rest % NP; int m = rest / NP;
  int ki = kk * 32 + (lq >> 4) * 4 + (j & 3) + 16 * (j >> 2);
  int c = p * 64 + ct * 16 + (lq & 15);
  float wv = (m == 0) ? Wid[(size_t)ki * COUT_ + c] : Wc[(size_t)((m - 1) * CIN_ + ki) * COUT_ + c];
  Wtf[i] = f2b(wv);
}

// ---------------- gather-reduce aggregation (CSR) ----------------
// aggXb[t*nloc+nl][c] = bf16( dinv_dst * sum_{e in list(t, lo+nl)} dinv_src * h[src][c] )
template <int CIN, typename TIN>
__global__ __launch_bounds__(256) void k_agg(const int* __restrict__ starts, const int* __restrict__ esrc,
                                             const float* __restrict__ dinv, const TIN* __restrict__ h,
                                             unsigned short* __restrict__ aggXb, int lo, int nloc) {
  constexpr int TPB = (CIN == 32) ? 32 : 64;
  constexpr int V = CIN / TPB;  // 1 or 2
  const int idx = blockIdx.x * 256 + threadIdx.x;
  const int bl = idx / TPB;
  const int lane = idx % TPB;
  if (bl >= 3 * nloc) return;
  const int t = bl / nloc;
  const int bin = t * NN + lo + (bl - t * nloc);
  const int s = (bin == 0) ? 0 : starts[bin - 1];
  const int e2 = starts[bin];
  float acc[V];
#pragma unroll
  for (int j = 0; j < V; j++) acc[j] = 0.f;
  for (int i = s; i < e2; i++) {
    const int sn = esrc[i];
    const float dv = dinv[(size_t)t * NN + sn];
    if (dv == 0.f) continue;
    const TIN* hp = h + (size_t)sn * CIN + lane * V;
#pragma unroll
    for (int j = 0; j < V; j++) {
      float v;
      if constexpr (sizeof(TIN) == 2) v = b2f(((const unsigned short*)hp)[j]);
      else v = ((const float*)hp)[j];
      acc[j] = fmaf(v, dv, acc[j]);
    }
  }
  const float dvd = dinv[bin];
  unsigned short* op = aggXb + (size_t)bl * CIN + lane * V;
#pragma unroll
  for (int j = 0; j < V; j++) op[j] = f2b(acc[j] * dvd);
}

// ---------------- fused finish via bf16 MFMA, LDS-staged weights ----------------
// 1D grid, XCD-swizzled (panels of one tile on same XCD). Per m: next m's panel
// weights are staged into the other LDS buffer (bulk coalesced) while current m's
// MFMAs read B-frags from LDS. Epilogue tile aliases the weight buffers.
template <int CIN, int COUT, bool INBF16, bool WRITEOUT, bool DOPOOL>
__global__ __launch_bounds__(256) void k_fin(
    const void* __restrict__ Xv, const unsigned short* __restrict__ aggXb,
    int lo, int nloc, int nt, const unsigned short* __restrict__ Wtf,
    const float* __restrict__ bid, const float* __restrict__ bc,
    unsigned short* __restrict__ outb, float* __restrict__ stats,
    float* __restrict__ pooled, const int* __restrict__ batch) {
  constexpr int NP = COUT / 64;
  constexpr int KK = CIN / 32;
  constexpr int PMF = KK * 256;                       // frags per (m,panel) slice
  constexpr int EPI = 64 * 65 * 4 + 2 * 4 * 64 * 4 + 64 * 4;  // tile + sred + sbatch
  constexpr int SMEM_BYTES = (2 * PMF * 16 > EPI) ? 2 * PMF * 16 : EPI;
  __shared__ __align__(16) char smem[SMEM_BYTES];
  short8b* wlds = (short8b*)smem;                     // [2][PMF]
  float (*tile)[65] = (float(*)[65])smem;             // epilogue aliases
  float* sred = (float*)(smem + 64 * 65 * 4);         // [2][4][64]
  int* sbatch = (int*)(smem + 64 * 65 * 4 + 2 * 4 * 64 * 4);

  // ---- XCD swizzle decode: i = xr8 + 8*(ti*NP + p) ----
  const int i = blockIdx.x;
  const int xr8 = i & 7;
  const int xq = i >> 3;
  const int p = xq % NP;
  const int ti = xq / NP;
  const int tileIdx = ti * 8 + xr8;
  if (tileIdx >= nt) return;
  const int ln0 = tileIdx * 64;
  const int n0 = lo + ln0;
  const int c0 = p * 64;
  const int tid = threadIdx.x, w = tid >> 6, l = tid & 63, lr = l & 15, lq = l >> 4;
  const int rA = w * 16 + lr;
  const int nA = n0 + rA;

  auto stage = [&](int m) {
    const short8b* g = (const short8b*)Wtf + (size_t)(m * NP + p) * PMF;
    short8b* d = wlds + (m & 1) * PMF;
#pragma unroll
    for (int ii = 0; ii < KK; ii++) d[ii * 256 + tid] = g[ii * 256 + tid];
  };

  f32x4 run[4];
#pragma unroll
  for (int ct = 0; ct < 4; ct++) run[ct] = (f32x4){0.f, 0.f, 0.f, 0.f};

  stage(0);
  __syncthreads();
#pragma unroll
  for (int m = 0; m < 4; m++) {
    if (m < 3) stage(m + 1);  // issue next slice early (overlaps MFMA below)
    // ---- hoisted A-fragment loads for this m ----
    ushort4 a0[KK], a1[KK];
    if (m > 0) {
      const unsigned short* ar = aggXb + ((size_t)(m - 1) * nloc + ln0 + rA) * CIN;
#pragma unroll
      for (int kk = 0; kk < KK; kk++) {
        a0[kk] = *(const ushort4*)(ar + kk * 32 + lq * 4);
        a1[kk] = *(const ushort4*)(ar + kk * 32 + 16 + lq * 4);
      }
    } else if (INBF16) {
      const unsigned short* xr = (const unsigned short*)Xv + (size_t)nA * CIN;
#pragma unroll
      for (int kk = 0; kk < KK; kk++) {
        a0[kk] = *(const ushort4*)(xr + kk * 32 + lq * 4);
        a1[kk] = *(const ushort4*)(xr + kk * 32 + 16 + lq * 4);
      }
    } else {
      const float* xr = (const float*)Xv + (size_t)nA * CIN;
#pragma unroll
      for (int kk = 0; kk < KK; kk++) {
        float4 v0 = *(const float4*)(xr + kk * 32 + lq * 4);
        float4 v1 = *(const float4*)(xr + kk * 32 + 16 + lq * 4);
        a0[kk] = make_ushort4(f2b(v0.x), f2b(v0.y), f2b(v0.z), f2b(v0.w));
        a1[kk] = make_ushort4(f2b(v1.x), f2b(v1.y), f2b(v1.z), f2b(v1.w));
      }
    }
    const short8b* wb = wlds + (m & 1) * PMF;
    f32x4 acc[4];
#pragma unroll
    for (int ct = 0; ct < 4; ct++) acc[ct] = (f32x4){0.f, 0.f, 0.f, 0.f};
#pragma unroll
    for (int kk = 0; kk < KK; kk++) {
      union { ushort4 u4[2]; short8b v; } fa;
      fa.u4[0] = a0[kk]; fa.u4[1] = a1[kk];
#pragma unroll
      for (int ct = 0; ct < 4; ct++)
        acc[ct] = __builtin_amdgcn_mfma_f32_16x16x32_bf16(fa.v, wb[kk * 256 + ct * 64 + l], acc[ct], 0, 0, 0);
    }
    const float* bp = (m == 0) ? bid : bc + (size_t)(m - 1) * COUT;
#pragma unroll
    for (int ct = 0; ct < 4; ct++) {
      float bb = bp[c0 + ct * 16 + lr];
#pragma unroll
      for (int j = 0; j < 4; j++) run[ct][j] += fmaxf(acc[ct][j] + bb, 0.f);
    }
    __syncthreads();  // stage(m+1) writes done; all waves done reading buf m
  }

  // ---- epilogue (smem now aliased as tile/sred/sbatch) ----
#pragma unroll
  for (int ct = 0; ct < 4; ct++)
#pragma unroll
    for (int j = 0; j < 4; j++) tile[w * 16 + lq * 4 + j][ct * 16 + lr] = run[ct][j];
  if (DOPOOL && tid < 64) sbatch[tid] = batch[n0 + tid];
  __syncthreads();

  if (WRITEOUT) {
    const int r = tid >> 2, cg = (tid & 3) * 16;
    ushort4 o[4];
#pragma unroll
    for (int g4 = 0; g4 < 4; g4++) {
      o[g4].x = f2b(tile[r][cg + g4 * 4 + 0]);
      o[g4].y = f2b(tile[r][cg + g4 * 4 + 1]);
      o[g4].z = f2b(tile[r][cg + g4 * 4 + 2]);
      o[g4].w = f2b(tile[r][cg + g4 * 4 + 3]);
    }
    ushort4* dst4 = (ushort4*)(outb + (size_t)(n0 + r) * COUT + c0 + cg);
#pragma unroll
    for (int g4 = 0; g4 < 4; g4++) dst4[g4] = o[g4];
  }
  {  // parallel stats + pool: thread = (rowgroup rg, col)
    const int col = tid & 63, rg = tid >> 6, r0 = rg * 16;
    float s = 0.f, ss = 0.f, gs = 0.f;
    int curg = DOPOOL ? sbatch[r0] : 0;
#pragma unroll
    for (int r = 0; r < 16; r++) {
      float v = tile[r0 + r][col];
      s += v; ss += v * v;
      if (DOPOOL) {
        int g = sbatch[r0 + r];
        if (g != curg) { atomAddF(&pooled[(size_t)curg * C2 + c0 + col], gs); gs = 0.f; curg = g; }
        gs += v;
      }
    }
    if (DOPOOL) atomAddF(&pooled[(size_t)curg * C2 + c0 + col], gs);
    sred[0 * 4 * 64 + rg * 64 + col] = s;
    sred[1 * 4 * 64 + rg * 64 + col] = ss;
  }
  __syncthreads();
  if (tid < 64) {
    float s4 = sred[0 + tid] + sred[64 + tid] + sred[128 + tid] + sred[192 + tid];
    float ss4 = sred[256 + tid] + sred[320 + tid] + sred[384 + tid] + sred[448 + tid];
    float* st = stats + (size_t)(tileIdx & (NREP - 1)) * 2 * COUT;
    atomAddF(&st[c0 + tid], s4);
    atomAddF(&st[COUT + c0 + tid], ss4);
  }
}

// ---------------- BN finalize (sums NREP replicas) -> per-channel scale/shift ----------------
__global__ __launch_bounds__(256) void k_bnfin(const float* __restrict__ stats, const float* __restrict__ gamma,
                                               const float* __restrict__ beta, float* __restrict__ sc,
                                               float* __restrict__ sh, int COUT) {
  int c = threadIdx.x;
  if (c < COUT) {
    float su = 0.f, ssu = 0.f;
    for (int r = 0; r < NREP; r++) {
      su += stats[(size_t)r * 2 * COUT + c];
      ssu += stats[(size_t)r * 2 * COUT + COUT + c];
    }
    const float invN = 1.f / (float)NN;
    float m = su * invN;
    float v = ssu * invN - m * m;
    float s = gamma[c] / sqrtf(v + 1e-5f);
    sc[c] = s;
    sh[c] = fmaf(-m, s, beta[c]);
  }
}

// ---------------- fold BN1 into out1 (bf16, in place) ----------------
__global__ __launch_bounds__(256) void k_bnfold(unsigned short* __restrict__ o, const float* __restrict__ sc,
                                                const float* __restrict__ sh) {
  size_t i8 = ((size_t)blockIdx.x * 256 + threadIdx.x) * 8;
  if (i8 >= (size_t)NN * C1) return;
  const int c = (int)(i8 & (C1 - 1));
  ushort4 a = *(ushort4*)(o + i8);
  ushort4 b = *(ushort4*)(o + i8 + 4);
  a.x = f2b(fmaf(b2f(a.x), sc[c + 0], sh[c + 0]));
  a.y = f2b(fmaf(b2f(a.y), sc[c + 1], sh[c + 1]));
  a.z = f2b(fmaf(b2f(a.z), sc[c + 2], sh[c + 2]));
  a.w = f2b(fmaf(b2f(a.w), sc[c + 3], sh[c + 3]));
  b.x = f2b(fmaf(b2f(b.x), sc[c + 4], sh[c + 4]));
  b.y = f2b(fmaf(b2f(b.y), sc[c + 5], sh[c + 5]));
  b.z = f2b(fmaf(b2f(b.z), sc[c + 6], sh[c + 6]));
  b.w = f2b(fmaf(b2f(b.w), sc[c + 7], sh[c + 7]));
  *(ushort4*)(o + i8) = a;
  *(ushort4*)(o + i8 + 4) = b;
}

// ---------------- MLP head: BN2 affine folded into pooled sums ----------------
__global__ __launch_bounds__(256) void k_mlp(const float* __restrict__ pooled, const float* __restrict__ counts,
                                             const float* __restrict__ sc2, const float* __restrict__ sh2,
                                             const float* __restrict__ Wf1, const float* __restrict__ bf1,
                                             const float* __restrict__ Wf2, const float* __restrict__ bf2,
                                             float* __restrict__ out) {
  __shared__ float feat[257];
  __shared__ float hid[256];
  const int g = blockIdx.x, t = threadIdx.x;
  const float cnt = counts[g];
  feat[t] = fmaf(sc2[t], pooled[(size_t)g * C2 + t], sh2[t] * cnt);
  if (t == 0) feat[256] = cnt * 0.025f;
  __syncthreads();
  float acc = bf1[t];
  for (int i = 0; i < 257; i++) acc = fmaf(feat[i], Wf1[(size_t)i * MLPH + t], acc);
  hid[t] = fmaxf(acc, 0.f);
  __syncthreads();
  if (t < NCLS) {
    float o = bf2[t];
    for (int j = 0; j < MLPH; j++) o = fmaf(hid[j], Wf2[(size_t)j * NCLS + t], o);
    out[(size_t)g * NCLS + t] = o;
  }
}

extern "C" void kernel_launch(void* const* d_in, const int* in_sizes, int n_in,
                              void* d_out, int out_size, void* d_ws, size_t ws_size,
                              hipStream_t stream) {
  const float* x = (const float*)d_in[0];
  const int* ei = (const int*)d_in[1];
  const int* et = (const int*)d_in[2];
  const int* batch = (const int*)d_in[3];
  const float* Wc0 = (const float*)d_in[4];
  const float* bc0 = (const float*)d_in[5];
  const float* Wid0 = (const float*)d_in[6];
  const float* bid0 = (const float*)d_in[7];
  const float* gm0 = (const float*)d_in[8];
  const float* bt0 = (const float*)d_in[9];
  const float* Wc1 = (const float*)d_in[10];
  const float* bc1 = (const float*)d_in[11];
  const float* Wid1 = (const float*)d_in[12];
  const float* bid1 = (const float*)d_in[13];
  const float* gm1 = (const float*)d_in[14];
  const float* bt1 = (const float*)d_in[15];
  const float* Wf1 = (const float*)d_in[16];
  const float* bf1 = (const float*)d_in[17];
  const float* Wf2 = (const float*)d_in[18];
  const float* bf2 = (const float*)d_in[19];
  const int* srcI = ei;
  const int* dstI = ei + NE;
  float* outp = (float*)d_out;

  char* ws = (char*)d_ws;
  size_t off = 0;
  auto take = [&](size_t bytes) -> char* {
    char* p = ws + off;
    off = (off + bytes + 255) & ~(size_t)255;
    return p;
  };
  float* dinv = (float*)take((size_t)NB * 4);
  int* cnt = (int*)take((size_t)NB * 4);
  int* starts = (int*)take((size_t)NB * 4);
  int* bsum = (int*)take((size_t)SCAN_NBLK * 4);
  int* esrc = (int*)take((size_t)NE * 4);
  float* stats1 = (float*)take((size_t)NREP * 2 * C1 * 4);
  float* stats2 = (float*)take((size_t)NREP * 2 * C2 * 4);
  float* sc1 = (float*)take(C1 * 4);
  float* sh1 = (float*)take(C1 * 4);
  float* sc2 = (float*)take(C2 * 4);
  float* sh2 = (float*)take(C2 * 4);
  float* counts = (float*)take((size_t)NG * 4);
  float* pooled = (float*)take((size_t)NG * C2 * 4);
  unsigned short* Wtf1 = (unsigned short*)take((size_t)4 * C0 * C1 * 2);
  unsigned short* Wtf2 = (unsigned short*)take((size_t)4 * C1 * C2 * 2);
  unsigned short* out1 = (unsigned short*)take((size_t)NN * C1 * 2);
  const size_t min_agg = (size_t)3 * 64 * C1 * 2;
  if (off + min_agg > ws_size) {
    k_fill<<<(out_size + 255) / 256, 256, 0, stream>>>(outp, out_size, 100.f);
    return;
  }
  unsigned short* aggXb = (unsigned short*)(ws + off);
  const size_t left = ws_size - off;
  long long ch1 = (long long)(left / ((size_t)3 * C0 * 2)) & ~63LL;
  long long ch2 = (long long)(left / ((size_t)3 * C1 * 2)) & ~63LL;
  if (ch1 > NN) ch1 = NN;
  if (ch2 > NN) ch2 = NN;

  dim3 blk(256);
  hipMemsetAsync(cnt, 0, (size_t)NB * 4, stream);
  hipMemsetAsync(stats1, 0, (size_t)NREP * 2 * C1 * 4, stream);
  hipMemsetAsync(stats2, 0, (size_t)NREP * 2 * C2 * 4, stream);
  hipMemsetAsync(counts, 0, (size_t)NG * 4, stream);
  hipMemsetAsync(pooled, 0, (size_t)NG * C2 * 4, stream);

  // ---- CSR build (histogram doubles as degree) ----
  k_hist<<<(NE + 255) / 256, blk, 0, stream>>>(dstI, et, cnt);
  k_dinvI<<<(NB + 255) / 256, blk, 0, stream>>>(cnt, dinv);
  k_counts<<<(NN + 255) / 256, blk, 0, stream>>>(batch, counts);
  k_scan1<<<SCAN_NBLK, blk, 0, stream>>>(cnt, starts, bsum);
  k_scan2<<<1, 64, 0, stream>>>(bsum);
  k_scan3<<<(NB + 255) / 256, blk, 0, stream>>>(starts, bsum);
  k_place<<<(NE + 255) / 256, blk, 0, stream>>>(srcI, dstI, et, starts, esrc);

  k_prepw<<<(4 * C0 * C1 + 255) / 256, blk, 0, stream>>>(Wid0, Wc0, Wtf1, C0, C1);
  k_prepw<<<(4 * C1 * C2 + 255) / 256, blk, 0, stream>>>(Wid1, Wc1, Wtf2, C1, C2);

  // ---- layer 1: x (f32, 32ch) -> out1 bf16 pre-BN (128ch) + stats1 ----
  for (long long lo = 0; lo < NN; lo += ch1) {
    const int nloc = (int)((NN - lo < ch1) ? (NN - lo) : ch1);
    const int nt = nloc / 64;
    const int nt8 = (nt + 7) & ~7;
    k_agg<C0, float><<<(3 * nloc * 32 + 255) / 256, blk, 0, stream>>>(starts, esrc, dinv, x, aggXb,
                                                                      (int)lo, nloc);
    k_fin<C0, C1, false, true, false><<<nt8 * (C1 / 64), blk, 0, stream>>>(
        x, aggXb, (int)lo, nloc, nt, Wtf1, bid0, bc0, out1, stats1, nullptr, nullptr);
  }
  k_bnfin<<<1, blk, 0, stream>>>(stats1, gm0, bt0, sc1, sh1, C1);
  k_bnfold<<<(int)(((size_t)NN * C1 / 8 + 255) / 256), blk, 0, stream>>>(out1, sc1, sh1);

  // ---- layer 2: out1 bf16 (BN1 folded) -> stats2 + pre-BN pooled ----
  for (long long lo = 0; lo < NN; lo += ch2) {
    const int nloc = (int)((NN - lo < ch2) ? (NN - lo) : ch2);
    const int nt = nloc / 64;
    const int nt8 = (nt + 7) & ~7;
    k_agg<C1, unsigned short><<<(3 * nloc * 64 + 255) / 256, blk, 0, stream>>>(starts, esrc, dinv, out1,
                                                                               aggXb, (int)lo, nloc);
    k_fin<C1, C2, true, false, true><<<nt8 * (C2 / 64), blk, 0, stream>>>(
        out1, aggXb, (int)lo, nloc, nt, Wtf2, bid1, bc1, nullptr, stats2, pooled, batch);
  }
  k_bnfin<<<1, blk, 0, stream>>>(stats2, gm1, bt1, sc2, sh2, C2);

  // ---- MLP head ----
  k_mlp<<<NG, blk, 0, stream>>>(pooled, counts, sc2, sh2, Wf1, bf1, Wf2, bf2, outp);
}